// Round 22
// baseline (35.414 us; speedup 1.0000x reference)
//
#include <hip/hip_runtime.h>

#define LEN_EPISODE 2048
#define TW 6.283185307179586
#define HH 0.16

// R22: producer/consumer with BARRIER-BATCHED sync (fixes R21's measured
// ~200 cyc/step publish overhead: per-step ds_write+threadfence+atomic and
// 6 waves spinning on an LDS counter).
// Wave 0 (SIMD 0, exclusive): integrates 16-step chunks into a double
// buffer -- one fire-and-forget ds_write_b64 per step, NO fence, NO atomics.
// Waves 1-3,5-7 (SIMDs 1-3): after each __syncthreads, emit chunk sb-1
// (15 Hermite + endpoint per step, transpose-stage, coalesced flush) while
// the producer fills the other buffer. Wave 4 idles (keeps SIMD 0 clean).
// 8 barriers total. Math bit-identical to R18/R21 => absmax must be 0.875.

#define STEPH() do {                                                        \
    const float f1 = Atil * rcf;                                            \
    const float f2 = __builtin_fmaf(nA2s, rsf, A2c * rcf);                  \
    const float f3 = __builtin_fmaf(nA3s, rsf, A3c * rcf);                  \
    rcn = __builtin_fmaf(nsdf, rsf, rcf * cdf);                             \
    rsn = __builtin_fmaf(sdf, rcf, rsf * cdf);                              \
    const float f4 = Atil * rcn;                                            \
    const float s1 = __builtin_amdgcn_sinf(U);                              \
    const float U2 = __builtin_fmaf(c13, V, U);                             \
    const float s2 = __builtin_amdgcn_sinf(U2);                             \
    const float k1w = __builtin_fmaf(nw2t, s1, __builtin_fmaf(ngam, V, f1)); \
    const float V2 = __builtin_fmaf(c13, k1w, V);                           \
    const float k2w = __builtin_fmaf(nw2t, s2, __builtin_fmaf(ngam, V2, f2)); \
    const float U3 = __builtin_fmaf(hh, V2, __builtin_fmaf(nc13, V, U));    \
    const float V3 = __builtin_fmaf(hh, k2w, __builtin_fmaf(nc13, k1w, V)); \
    const float s3 = __builtin_amdgcn_sinf(U3);                             \
    const float k3w = __builtin_fmaf(nw2t, s3, __builtin_fmaf(ngam, V3, f3)); \
    const float U4 = __builtin_fmaf(hh, (V - V2) + V3, U);                  \
    const float V4 = __builtin_fmaf(hh, (k1w - k2w) + k3w, V);              \
    const float s4 = __builtin_amdgcn_sinf(U4);                             \
    const float k4w = __builtin_fmaf(nw2t, s4, __builtin_fmaf(ngam, V4, f4)); \
    Un = __builtin_fmaf(h8, __builtin_fmaf(3.0f, V2 + V3, V) + V4, U);      \
    Vn = __builtin_fmaf(h8, __builtin_fmaf(3.0f, k2w + k3w, k1w) + k4w, V); \
} while (0)

// Cubic Hermite basis (compile-time doubles), radians+h folded in.
#define B00(t) ((1.0-(t))*(1.0-(t))*(1.0+2.0*(t)))
#define B10(t) ((t)*(1.0-(t))*(1.0-(t)))
#define B01(t) ((t)*(t)*(3.0-2.0*(t)))
#define B11(t) ((t)*(t)*((t)-1.0))
#define HERMT(t)                                                              \
    __builtin_fmaf((float)(TW * B00(t)), U,                                   \
    __builtin_fmaf((float)(TW * B10(t) * HH), V,                              \
    __builtin_fmaf((float)(TW * B01(t)), Un, (float)(TW * B11(t) * HH) * Vn)))

#define EMIT15(dst) do {                                                      \
    (dst)[0]  = HERMT( 1.0/16.0); (dst)[1]  = HERMT( 2.0/16.0);               \
    (dst)[2]  = HERMT( 3.0/16.0); (dst)[3]  = HERMT( 4.0/16.0);               \
    (dst)[4]  = HERMT( 5.0/16.0); (dst)[5]  = HERMT( 6.0/16.0);               \
    (dst)[6]  = HERMT( 7.0/16.0); (dst)[7]  = HERMT( 8.0/16.0);               \
    (dst)[8]  = HERMT( 9.0/16.0); (dst)[9]  = HERMT(10.0/16.0);               \
    (dst)[10] = HERMT(11.0/16.0); (dst)[11] = HERMT(12.0/16.0);               \
    (dst)[12] = HERMT(13.0/16.0); (dst)[13] = HERMT(14.0/16.0);               \
    (dst)[14] = HERMT(15.0/16.0);                                             \
} while (0)

#define COMMIT() do { U = Un; V = Vn; rcf = rcn; rsf = rsn; } while (0)

__global__ __launch_bounds__(512) void pend_kernel(
    const float* __restrict__ init,    // (B, 2)
    const float* __restrict__ params,  // (B, 4)
    float* __restrict__ out,           // (B, LEN_EPISODE)
    int B)
{
    __shared__ float2 buf[2][17][64];  // [dbuf][state 0..16][lane]
    __shared__ float  stag[6][16 * 65];// per-emitter transpose staging

    const int tid  = threadIdx.x;
    const int lane = tid & 63;
    const int wv   = tid >> 6;          // 0 producer; 1-3,5-7 emitters; 4 idle
    const int b = blockIdx.x * 64 + lane;   // exact cover of B

    const float twopi  = 6.283185307179586f;
    const float inv2pi = 0.15915494309189535f;

    const float2 ic = *reinterpret_cast<const float2*>(init + 2 * b);

    // ---------------- producer state (wave 0 only) ----------------
    float U, V, rcf, rsf;
    float hh = 0, c13 = 0, nc13 = 0, h8 = 0, ngam = 0, nw2t = 0, Atil = 0;
    float cdf = 0, sdf = 0, nsdf = 0, A2c = 0, nA2s = 0, A3c = 0, nA3s = 0;

    if (wv == 0) {
        const float4 p = *reinterpret_cast<const float4*>(params + 4 * b);
        const float omega = p.x, gamma = p.y, A = p.z, phi = p.w;
        U = ic.x * inv2pi;
        V = ic.y * inv2pi;
        hh   = 0.16f;
        c13  = (float)(0.16 / 3.0);
        nc13 = -c13;
        h8   = 0.02f;
        ngam = -gamma;
        nw2t = -(omega * omega) * inv2pi;
        Atil = A * omega * omega * inv2pi;
        const double c_d = 6.283185307179586476925287 * (double)phi;
        cdf  = (float)::cos(c_d * 0.16);
        sdf  = (float)::sin(c_d * 0.16);
        nsdf = -sdf;
        A2c  = Atil * (float)::cos(c_d * (0.16 / 3.0));
        nA2s = -Atil * (float)::sin(c_d * (0.16 / 3.0));
        A3c  = Atil * (float)::cos(c_d * (0.32 / 3.0));
        nA3s = -Atil * (float)::sin(c_d * (0.32 / 3.0));
        rcf = 1.0f; rsf = 0.0f;
    }

    // ---------------- emitter constants ----------------
    const int eid = (wv < 4) ? (wv - 1) : (wv - 2);   // 0..5 for emitter waves
    const int r16 = lane >> 2;          // flush: row within 16-row group
    const int q2  = lane & 3;           // flush: 16B column chunk
    float* __restrict__ outblk = out + (size_t)(blockIdx.x * 64) * LEN_EPISODE;

    // ---------------- pipeline: 8 chunks of 16 steps ----------------
    for (int sb = 0; sb < 8; ++sb) {
        if (wv == 0) {
            // produce chunk sb into buf[sb&1]
            float Un, Vn, rcn, rsn;
#pragma unroll 4
            for (int j = 0; j < 16; ++j) {
                buf[sb & 1][j][lane] = make_float2(U, V);
                STEPH(); COMMIT();
            }
            buf[sb & 1][16][lane] = make_float2(U, V);
        } else if (wv != 4 && sb > 0) {
            // emit chunk sb-1 from buf[(sb-1)&1]
            const int c = sb - 1;
            float* __restrict__ stg = &stag[eid][0];
            float va[16];
            for (int j = eid; j < 16; j += 6) {
                const int k = (c << 4) + j;
                const float2 s0 = buf[c & 1][j][lane];
                const float2 s1 = buf[c & 1][j + 1][lane];
                const float U = s0.x, V = s0.y, Un = s1.x, Vn = s1.y;
                va[0] = (k == 0) ? ic.x : twopi * U;
                EMIT15(va + 1);
#pragma unroll
                for (int m = 0; m < 16; ++m)
                    stg[m * 65 + lane] = va[m];
                const int colb = k << 4;
#pragma unroll
                for (int rb = 0; rb < 4; ++rb) {
                    const int row = (rb << 4) + r16;
                    float4 v;
                    v.x = stg[(4 * q2 + 0) * 65 + row];
                    v.y = stg[(4 * q2 + 1) * 65 + row];
                    v.z = stg[(4 * q2 + 2) * 65 + row];
                    v.w = stg[(4 * q2 + 3) * 65 + row];
                    *reinterpret_cast<float4*>(outblk + (size_t)row * LEN_EPISODE + colb + 4 * q2) = v;
                }
            }
        }
        __syncthreads();
    }

    // ---------------- drain: emit final chunk 7 ----------------
    if (wv != 0 && wv != 4) {
        const int c = 7;
        float* __restrict__ stg = &stag[eid][0];
        float va[16];
        for (int j = eid; j < 16; j += 6) {
            const int k = (c << 4) + j;
            const float2 s0 = buf[c & 1][j][lane];
            const float2 s1 = buf[c & 1][j + 1][lane];
            const float U = s0.x, V = s0.y, Un = s1.x, Vn = s1.y;
            va[0] = (k == 0) ? ic.x : twopi * U;
            EMIT15(va + 1);
#pragma unroll
            for (int m = 0; m < 16; ++m)
                stg[m * 65 + lane] = va[m];
            const int colb = k << 4;
#pragma unroll
            for (int rb = 0; rb < 4; ++rb) {
                const int row = (rb << 4) + r16;
                float4 v;
                v.x = stg[(4 * q2 + 0) * 65 + row];
                v.y = stg[(4 * q2 + 1) * 65 + row];
                v.z = stg[(4 * q2 + 2) * 65 + row];
                v.w = stg[(4 * q2 + 3) * 65 + row];
                *reinterpret_cast<float4*>(outblk + (size_t)row * LEN_EPISODE + colb + 4 * q2) = v;
            }
        }
    }
    // final endpoint (output index 2048) intentionally discarded
}

extern "C" void kernel_launch(void* const* d_in, const int* in_sizes, int n_in,
                              void* d_out, int out_size, void* d_ws, size_t ws_size,
                              hipStream_t stream) {
    const float* init   = (const float*)d_in[0];
    const float* params = (const float*)d_in[1];
    float* out = (float*)d_out;
    const int B = in_sizes[0] / 2;  // 16384

    const int block = 512;              // wave 0 producer, 6 emitters, 1 idle
    const int grid  = B / 64;           // 256 blocks, exact cover
    pend_kernel<<<grid, block, 0, stream>>>(init, params, out, B);
}

// Round 24
// 31.050 us; speedup vs baseline: 1.1406x; 1.1406x over previous
//
#include <hip/hip_runtime.h>

#define LEN_EPISODE 2048
#define TW 6.283185307179586
#define HH 0.16

// R24 = R23 with the ring-overflow race class ELIMINATED: no-wraparound ring.
// R23's corruption: producer (sped to ~410cyc/step by amortized publish)
// outran HBM-write-throttled emitters; 64-deep ring slot (k&63) got
// overwritten before being read (R21 only passed because its slower producer
// left 38k cyc of grace). Fix: ring[129] -- one slot per state, written
// exactly once, read only after publish. No flow control needed by
// construction. LDS: 66KB ring + 25.4KB staging ~= 92KB < 160KB (1 block/CU
// as before). Publish: ring ds_write per step (fire-and-forget), RELEASE
// counter store every 4 steps. Math bit-identical to R18 => absmax 0.875.

#define STEPH() do {                                                        \
    const float f1 = Atil * rcf;                                            \
    const float f2 = __builtin_fmaf(nA2s, rsf, A2c * rcf);                  \
    const float f3 = __builtin_fmaf(nA3s, rsf, A3c * rcf);                  \
    rcn = __builtin_fmaf(nsdf, rsf, rcf * cdf);                             \
    rsn = __builtin_fmaf(sdf, rcf, rsf * cdf);                              \
    const float f4 = Atil * rcn;                                            \
    const float s1 = __builtin_amdgcn_sinf(U);                              \
    const float U2 = __builtin_fmaf(c13, V, U);                             \
    const float s2 = __builtin_amdgcn_sinf(U2);                             \
    const float k1w = __builtin_fmaf(nw2t, s1, __builtin_fmaf(ngam, V, f1)); \
    const float V2 = __builtin_fmaf(c13, k1w, V);                           \
    const float k2w = __builtin_fmaf(nw2t, s2, __builtin_fmaf(ngam, V2, f2)); \
    const float U3 = __builtin_fmaf(hh, V2, __builtin_fmaf(nc13, V, U));    \
    const float V3 = __builtin_fmaf(hh, k2w, __builtin_fmaf(nc13, k1w, V)); \
    const float s3 = __builtin_amdgcn_sinf(U3);                             \
    const float k3w = __builtin_fmaf(nw2t, s3, __builtin_fmaf(ngam, V3, f3)); \
    const float U4 = __builtin_fmaf(hh, (V - V2) + V3, U);                  \
    const float V4 = __builtin_fmaf(hh, (k1w - k2w) + k3w, V);              \
    const float s4 = __builtin_amdgcn_sinf(U4);                             \
    const float k4w = __builtin_fmaf(nw2t, s4, __builtin_fmaf(ngam, V4, f4)); \
    Un = __builtin_fmaf(h8, __builtin_fmaf(3.0f, V2 + V3, V) + V4, U);      \
    Vn = __builtin_fmaf(h8, __builtin_fmaf(3.0f, k2w + k3w, k1w) + k4w, V); \
} while (0)

// Cubic Hermite basis (compile-time doubles), radians+h folded in.
#define B00(t) ((1.0-(t))*(1.0-(t))*(1.0+2.0*(t)))
#define B10(t) ((t)*(1.0-(t))*(1.0-(t)))
#define B01(t) ((t)*(t)*(3.0-2.0*(t)))
#define B11(t) ((t)*(t)*((t)-1.0))
#define HERMT(t)                                                              \
    __builtin_fmaf((float)(TW * B00(t)), U,                                   \
    __builtin_fmaf((float)(TW * B10(t) * HH), V,                              \
    __builtin_fmaf((float)(TW * B01(t)), Un, (float)(TW * B11(t) * HH) * Vn)))

#define EMIT15(dst) do {                                                      \
    (dst)[0]  = HERMT( 1.0/16.0); (dst)[1]  = HERMT( 2.0/16.0);               \
    (dst)[2]  = HERMT( 3.0/16.0); (dst)[3]  = HERMT( 4.0/16.0);               \
    (dst)[4]  = HERMT( 5.0/16.0); (dst)[5]  = HERMT( 6.0/16.0);               \
    (dst)[6]  = HERMT( 7.0/16.0); (dst)[7]  = HERMT( 8.0/16.0);               \
    (dst)[8]  = HERMT( 9.0/16.0); (dst)[9]  = HERMT(10.0/16.0);               \
    (dst)[10] = HERMT(11.0/16.0); (dst)[11] = HERMT(12.0/16.0);               \
    (dst)[12] = HERMT(13.0/16.0); (dst)[13] = HERMT(14.0/16.0);               \
    (dst)[14] = HERMT(15.0/16.0);                                             \
} while (0)

#define COMMIT() do { U = Un; V = Vn; rcf = rcn; rsf = rsn; } while (0)

__global__ __launch_bounds__(512) void pend_kernel(
    const float* __restrict__ init,    // (B, 2)
    const float* __restrict__ params,  // (B, 4)
    float* __restrict__ out,           // (B, LEN_EPISODE)
    int B)
{
    __shared__ float2 ring[129][64];   // [state k][lane] -- written ONCE each
    __shared__ float  stag[6][16 * 65];// per-emitter transpose staging
    __shared__ int    cnt;             // number of published states

    const int tid  = threadIdx.x;
    const int lane = tid & 63;
    const int wv   = tid >> 6;          // 0 = producer; 1-3,5-7 = emitters
    const int b = blockIdx.x * 64 + lane;

    const float twopi  = 6.283185307179586f;
    const float inv2pi = 0.15915494309189535f;

    const float2 ic = *reinterpret_cast<const float2*>(init + 2 * b);

    if (tid == 0) cnt = 0;
    __syncthreads();                    // cnt initialized before anyone spins

    if (wv == 0) {
        // ---------------- producer: pure integration ----------------
        const float4 p  = *reinterpret_cast<const float4*>(params + 4 * b);
        const float omega = p.x, gamma = p.y, A = p.z, phi = p.w;

        float U = ic.x * inv2pi;
        float V = ic.y * inv2pi;

        const float hh   = 0.16f;
        const float c13  = (float)(0.16 / 3.0);
        const float nc13 = -c13;
        const float h8   = 0.02f;
        const float ngam = -gamma;
        const float nw2t = -(omega * omega) * inv2pi;
        const float Atil = A * omega * omega * inv2pi;

        const double c_d = 6.283185307179586476925287 * (double)phi;
        const float cdf  = (float)::cos(c_d * 0.16);
        const float sdf  = (float)::sin(c_d * 0.16);
        const float nsdf = -sdf;
        const float A2c  = Atil * (float)::cos(c_d * (0.16 / 3.0));
        const float nA2s = -Atil * (float)::sin(c_d * (0.16 / 3.0));
        const float A3c  = Atil * (float)::cos(c_d * (0.32 / 3.0));
        const float nA3s = -Atil * (float)::sin(c_d * (0.32 / 3.0));

        float rcf = 1.0f, rsf = 0.0f;
        float Un, Vn, rcn, rsn;

        for (int k4 = 0; k4 < 128; k4 += 4) {
#pragma unroll
            for (int j = 0; j < 4; ++j) {
                ring[k4 + j][lane] = make_float2(U, V);
                STEPH(); COMMIT();
            }
            // RELEASE orders the 4 ring writes above; one drain per 4 steps.
            if (lane == 0)
                __hip_atomic_store(&cnt, k4 + 4, __ATOMIC_RELEASE,
                                   __HIP_MEMORY_SCOPE_WORKGROUP);
        }
        ring[128][lane] = make_float2(U, V);            // final endpoint state
        if (lane == 0)
            __hip_atomic_store(&cnt, 129, __ATOMIC_RELEASE,
                               __HIP_MEMORY_SCOPE_WORKGROUP);
    } else if (wv != 4) {
        // ---------------- emitters: Hermite + transposed flush ----------------
        const int eid = (wv < 4) ? (wv - 1) : (wv - 2);   // 0..5
        float* __restrict__ stg = &stag[eid][0];
        const int r16 = lane >> 2;          // row within 16-row group
        const int q2  = lane & 3;           // 16B column chunk
        float* __restrict__ outblk = out + (size_t)(blockIdx.x * 64) * LEN_EPISODE;

        float va[16];

        for (int k = eid; k < 128; k += 6) {
            // wait until states k and k+1 are published
            while (__hip_atomic_load(&cnt, __ATOMIC_ACQUIRE,
                                     __HIP_MEMORY_SCOPE_WORKGROUP) < k + 2) {
                __builtin_amdgcn_s_sleep(2);
            }
            const float2 s0 = ring[k][lane];
            const float2 s1 = ring[k + 1][lane];
            const float U = s0.x, V = s0.y, Un = s1.x, Vn = s1.y;

            va[0] = (k == 0) ? ic.x : twopi * U;    // previous endpoint
            EMIT15(va + 1);

#pragma unroll
            for (int j = 0; j < 16; ++j)
                stg[j * 65 + lane] = va[j];

            const int colb = k << 4;
#pragma unroll
            for (int rb = 0; rb < 4; ++rb) {
                const int row = (rb << 4) + r16;
                float4 v;
                v.x = stg[(4 * q2 + 0) * 65 + row];
                v.y = stg[(4 * q2 + 1) * 65 + row];
                v.z = stg[(4 * q2 + 2) * 65 + row];
                v.w = stg[(4 * q2 + 3) * 65 + row];
                *reinterpret_cast<float4*>(outblk + (size_t)row * LEN_EPISODE + colb + 4 * q2) = v;
            }
        }
    }
    // wave 4 (shares SIMD 0 with producer): exits immediately
    // final endpoint (output index 2048) intentionally discarded
}

extern "C" void kernel_launch(void* const* d_in, const int* in_sizes, int n_in,
                              void* d_out, int out_size, void* d_ws, size_t ws_size,
                              hipStream_t stream) {
    const float* init   = (const float*)d_in[0];
    const float* params = (const float*)d_in[1];
    float* out = (float*)d_out;
    const int B = in_sizes[0] / 2;  // 16384

    const int block = 512;              // wave 0 producer, 6 emitter waves
    const int grid  = B / 64;           // 256 blocks, exact cover
    pend_kernel<<<grid, block, 0, stream>>>(init, params, out, B);
}

// Round 25
// 27.891 us; speedup vs baseline: 1.2697x; 1.1132x over previous
//
#include <hip/hip_runtime.h>

#define LEN_EPISODE 2048
#define TW 6.283185307179586
#define HH 0.16

// R25 = R24 with PAIR-EMISSION: each emitter owns step-pairs (2p,2p+1) and
// flushes 64 rows x 128B FULL LINES (R13's validated pattern).
// Diagnosis: since R16 flushes were 64B half-lines, and adjacent halves come
// from different waves ~6 emit-iters apart; with 512KB/block streaming
// through 4MB/XCD L2, partial lines can evict before completion -> up to 2x
// DRAM write amplification (~268MB ~ 40us write stream) = R24's unexplained
// ~8us. Producer/ring/publish identical to R24 => absmax must be 0.875.

#define STEPH() do {                                                        \
    const float f1 = Atil * rcf;                                            \
    const float f2 = __builtin_fmaf(nA2s, rsf, A2c * rcf);                  \
    const float f3 = __builtin_fmaf(nA3s, rsf, A3c * rcf);                  \
    rcn = __builtin_fmaf(nsdf, rsf, rcf * cdf);                             \
    rsn = __builtin_fmaf(sdf, rcf, rsf * cdf);                              \
    const float f4 = Atil * rcn;                                            \
    const float s1 = __builtin_amdgcn_sinf(U);                              \
    const float U2 = __builtin_fmaf(c13, V, U);                             \
    const float s2 = __builtin_amdgcn_sinf(U2);                             \
    const float k1w = __builtin_fmaf(nw2t, s1, __builtin_fmaf(ngam, V, f1)); \
    const float V2 = __builtin_fmaf(c13, k1w, V);                           \
    const float k2w = __builtin_fmaf(nw2t, s2, __builtin_fmaf(ngam, V2, f2)); \
    const float U3 = __builtin_fmaf(hh, V2, __builtin_fmaf(nc13, V, U));    \
    const float V3 = __builtin_fmaf(hh, k2w, __builtin_fmaf(nc13, k1w, V)); \
    const float s3 = __builtin_amdgcn_sinf(U3);                             \
    const float k3w = __builtin_fmaf(nw2t, s3, __builtin_fmaf(ngam, V3, f3)); \
    const float U4 = __builtin_fmaf(hh, (V - V2) + V3, U);                  \
    const float V4 = __builtin_fmaf(hh, (k1w - k2w) + k3w, V);              \
    const float s4 = __builtin_amdgcn_sinf(U4);                             \
    const float k4w = __builtin_fmaf(nw2t, s4, __builtin_fmaf(ngam, V4, f4)); \
    Un = __builtin_fmaf(h8, __builtin_fmaf(3.0f, V2 + V3, V) + V4, U);      \
    Vn = __builtin_fmaf(h8, __builtin_fmaf(3.0f, k2w + k3w, k1w) + k4w, V); \
} while (0)

// Cubic Hermite basis (compile-time doubles), radians+h folded in.
#define B00(t) ((1.0-(t))*(1.0-(t))*(1.0+2.0*(t)))
#define B10(t) ((t)*(1.0-(t))*(1.0-(t)))
#define B01(t) ((t)*(t)*(3.0-2.0*(t)))
#define B11(t) ((t)*(t)*((t)-1.0))
#define HERMT(t)                                                              \
    __builtin_fmaf((float)(TW * B00(t)), U,                                   \
    __builtin_fmaf((float)(TW * B10(t) * HH), V,                              \
    __builtin_fmaf((float)(TW * B01(t)), Un, (float)(TW * B11(t) * HH) * Vn)))

#define EMIT15(dst) do {                                                      \
    (dst)[0]  = HERMT( 1.0/16.0); (dst)[1]  = HERMT( 2.0/16.0);               \
    (dst)[2]  = HERMT( 3.0/16.0); (dst)[3]  = HERMT( 4.0/16.0);               \
    (dst)[4]  = HERMT( 5.0/16.0); (dst)[5]  = HERMT( 6.0/16.0);               \
    (dst)[6]  = HERMT( 7.0/16.0); (dst)[7]  = HERMT( 8.0/16.0);               \
    (dst)[8]  = HERMT( 9.0/16.0); (dst)[9]  = HERMT(10.0/16.0);               \
    (dst)[10] = HERMT(11.0/16.0); (dst)[11] = HERMT(12.0/16.0);               \
    (dst)[12] = HERMT(13.0/16.0); (dst)[13] = HERMT(14.0/16.0);               \
    (dst)[14] = HERMT(15.0/16.0);                                             \
} while (0)

#define COMMIT() do { U = Un; V = Vn; rcf = rcn; rsf = rsn; } while (0)

__global__ __launch_bounds__(512) void pend_kernel(
    const float* __restrict__ init,    // (B, 2)
    const float* __restrict__ params,  // (B, 4)
    float* __restrict__ out,           // (B, LEN_EPISODE)
    int B)
{
    __shared__ float2 ring[129][64];   // [state k][lane] -- written ONCE each
    __shared__ float  stag[6][32 * 65];// per-emitter transpose staging (pairs)
    __shared__ int    cnt;             // number of published states

    const int tid  = threadIdx.x;
    const int lane = tid & 63;
    const int wv   = tid >> 6;          // 0 = producer; 1-3,5-7 = emitters
    const int b = blockIdx.x * 64 + lane;

    const float twopi  = 6.283185307179586f;
    const float inv2pi = 0.15915494309189535f;

    const float2 ic = *reinterpret_cast<const float2*>(init + 2 * b);

    if (tid == 0) cnt = 0;
    __syncthreads();                    // cnt initialized before anyone spins

    if (wv == 0) {
        // ---------------- producer: pure integration ----------------
        const float4 p  = *reinterpret_cast<const float4*>(params + 4 * b);
        const float omega = p.x, gamma = p.y, A = p.z, phi = p.w;

        float U = ic.x * inv2pi;
        float V = ic.y * inv2pi;

        const float hh   = 0.16f;
        const float c13  = (float)(0.16 / 3.0);
        const float nc13 = -c13;
        const float h8   = 0.02f;
        const float ngam = -gamma;
        const float nw2t = -(omega * omega) * inv2pi;
        const float Atil = A * omega * omega * inv2pi;

        const double c_d = 6.283185307179586476925287 * (double)phi;
        const float cdf  = (float)::cos(c_d * 0.16);
        const float sdf  = (float)::sin(c_d * 0.16);
        const float nsdf = -sdf;
        const float A2c  = Atil * (float)::cos(c_d * (0.16 / 3.0));
        const float nA2s = -Atil * (float)::sin(c_d * (0.16 / 3.0));
        const float A3c  = Atil * (float)::cos(c_d * (0.32 / 3.0));
        const float nA3s = -Atil * (float)::sin(c_d * (0.32 / 3.0));

        float rcf = 1.0f, rsf = 0.0f;
        float Un, Vn, rcn, rsn;

        for (int k4 = 0; k4 < 128; k4 += 4) {
#pragma unroll
            for (int j = 0; j < 4; ++j) {
                ring[k4 + j][lane] = make_float2(U, V);
                STEPH(); COMMIT();
            }
            // RELEASE orders the 4 ring writes above; one drain per 4 steps.
            if (lane == 0)
                __hip_atomic_store(&cnt, k4 + 4, __ATOMIC_RELEASE,
                                   __HIP_MEMORY_SCOPE_WORKGROUP);
        }
        ring[128][lane] = make_float2(U, V);            // final endpoint state
        if (lane == 0)
            __hip_atomic_store(&cnt, 129, __ATOMIC_RELEASE,
                               __HIP_MEMORY_SCOPE_WORKGROUP);
    } else if (wv != 4) {
        // -------- emitters: step-PAIRS, full 128B-line flushes --------
        const int eid = (wv < 4) ? (wv - 1) : (wv - 2);   // 0..5
        float* __restrict__ stg = &stag[eid][0];
        const int r8 = lane >> 3;           // row within 8-row group
        const int q  = lane & 7;            // 16B column chunk (8 per 32 cols)
        float* __restrict__ outblk = out + (size_t)(blockIdx.x * 64) * LEN_EPISODE;

        float va[32];

        for (int pr = eid; pr < 64; pr += 6) {
            const int k = pr << 1;          // first step of the pair
            // need states k, k+1, k+2
            while (__hip_atomic_load(&cnt, __ATOMIC_ACQUIRE,
                                     __HIP_MEMORY_SCOPE_WORKGROUP) < k + 3) {
                __builtin_amdgcn_s_sleep(2);
            }
            const float2 s0 = ring[k][lane];
            const float2 s1 = ring[k + 1][lane];
            const float2 s2 = ring[k + 2][lane];

            va[0] = (k == 0) ? ic.x : twopi * s0.x;     // previous endpoint
            {   // first half: step k (states s0 -> s1)
                const float U = s0.x, V = s0.y, Un = s1.x, Vn = s1.y;
                EMIT15(va + 1);
            }
            va[16] = twopi * s1.x;                      // endpoint of step k
            {   // second half: step k+1 (states s1 -> s2)
                const float U = s1.x, V = s1.y, Un = s2.x, Vn = s2.y;
                EMIT15(va + 17);
            }

#pragma unroll
            for (int j = 0; j < 32; ++j)
                stg[j * 65 + lane] = va[j];

            const int colb = k << 4;        // 32 contiguous output columns
#pragma unroll
            for (int rb = 0; rb < 8; ++rb) {
                const int row = (rb << 3) + r8;
                float4 v;
                v.x = stg[(4 * q + 0) * 65 + row];
                v.y = stg[(4 * q + 1) * 65 + row];
                v.z = stg[(4 * q + 2) * 65 + row];
                v.w = stg[(4 * q + 3) * 65 + row];
                *reinterpret_cast<float4*>(outblk + (size_t)row * LEN_EPISODE + colb + 4 * q) = v;
            }
        }
    }
    // wave 4 (shares SIMD 0 with producer): exits immediately
    // final endpoint (output index 2048) intentionally discarded
}

extern "C" void kernel_launch(void* const* d_in, const int* in_sizes, int n_in,
                              void* d_out, int out_size, void* d_ws, size_t ws_size,
                              hipStream_t stream) {
    const float* init   = (const float*)d_in[0];
    const float* params = (const float*)d_in[1];
    float* out = (float*)d_out;
    const int B = in_sizes[0] / 2;  // 16384

    const int block = 512;              // wave 0 producer, 6 emitter waves
    const int grid  = B / 64;           // 256 blocks, exact cover
    pend_kernel<<<grid, block, 0, stream>>>(init, params, out, B);
}